// Round 6
// baseline (339.520 us; speedup 1.0000x reference)
//
#include <hip/hip_runtime.h>
#include <cstdint>

typedef __attribute__((ext_vector_type(8))) short bf16x8;
typedef __attribute__((ext_vector_type(4))) float f32x4;
typedef __attribute__((ext_vector_type(16))) float f32x16;

__device__ inline unsigned short f2bf(float f) {
  uint32_t u = __float_as_uint(f);
  uint32_t lsb = (u >> 16) & 1u;
  u += 0x7fffu + lsb;
  return (unsigned short)(u >> 16);
}
__device__ inline float bf2f(unsigned short b) {
  return __uint_as_float(((uint32_t)b) << 16);
}
__device__ inline uint32_t cvt_pk_bf16(float lo, float hi) {
  uint32_t r;
  asm volatile("v_cvt_pk_bf16_f32 %0, %1, %2" : "=v"(r) : "v"(lo), "v"(hi));
  return r;
}

#define GLOAD16(gp, lp)                                                        \
  __builtin_amdgcn_global_load_lds(                                            \
      (const __attribute__((address_space(1))) void*)(gp),                     \
      (__attribute__((address_space(3))) void*)(lp), 16, 0, 0)

// ---------------------------------------------------------------- fused f32->bf16 convert
// segments: x(8388608) -> xb; Wq/Wk/Wv(4194304 each) -> wqkv contiguous; Wo -> wo
__global__ void cvt_all(const float* __restrict__ x, const float* __restrict__ wq,
                        const float* __restrict__ wk, const float* __restrict__ wv,
                        const float* __restrict__ wos, unsigned short* __restrict__ xb,
                        unsigned short* __restrict__ wqkv,
                        unsigned short* __restrict__ wo) {
  size_t e = ((size_t)blockIdx.x * 256 + threadIdx.x) * 4;
  const float* src;
  unsigned short* dst;
  if (e < 8388608) {
    src = x + e;
    dst = xb + e;
  } else {
    size_t r = e - 8388608;
    int k = (int)(r >> 22);
    size_t off = r & 4194303;
    if (k == 0) { src = wq + off; dst = wqkv + r; }
    else if (k == 1) { src = wk + off; dst = wqkv + r; }
    else if (k == 2) { src = wv + off; dst = wqkv + r; }
    else { src = wos + off; dst = wo + off; }
  }
  float4 v = *(const float4*)src;
  unsigned short o[4] = {f2bf(v.x), f2bf(v.y), f2bf(v.z), f2bf(v.w)};
  *(uint64_t*)dst = *(const uint64_t*)o;
}

// ---------------------------------------------------------------- rope table
__global__ void rope_table_k(float* __restrict__ ctab, float* __restrict__ stab) {
  int i = blockIdx.x * 256 + threadIdx.x;  // 2048*64 entries
  int s = i >> 6, j = i & 63;
  float invf = expf(-(float)j * (9.210340371976184f / 64.0f));
  float ang = (float)s * invf;
  ctab[i] = cosf(ang);
  stab[i] = sinf(ang);
}

// ---------------------------------------------------------------- rope apply (in-place, vectorized x4)
// rows: [buf(2)][bh(32)][s(2048)], 16 rows per 256-thread block
__global__ void rope_apply_k(unsigned short* __restrict__ qb,
                             unsigned short* __restrict__ kb,
                             const float* __restrict__ ctab,
                             const float* __restrict__ stab) {
  int row = blockIdx.x * 16 + (threadIdx.x >> 4);
  int c = (threadIdx.x & 15) * 4;
  int s = row & 2047;
  int bh = (row >> 11) & 31;
  int isK = row >> 16;
  unsigned short* base = isK ? kb : qb;
  float qs = isK ? 1.0f : (0.08838834764831845f * 1.4426950408889634f);
  unsigned short* p = base + ((size_t)bh * 2048 + s) * 128;
  float4 cv = *(const float4*)(ctab + s * 64 + c);
  float4 sv = *(const float4*)(stab + s * 64 + c);
  union { unsigned short u[4]; uint64_t q; } a, b2, oa, ob;
  a.q = *(const uint64_t*)(p + c);
  b2.q = *(const uint64_t*)(p + 64 + c);
  float cc[4] = {cv.x, cv.y, cv.z, cv.w};
  float ss[4] = {sv.x, sv.y, sv.z, sv.w};
#pragma unroll
  for (int i = 0; i < 4; i++) {
    float x1 = bf2f(a.u[i]), x2 = bf2f(b2.u[i]);
    oa.u[i] = f2bf((x1 * cc[i] - x2 * ss[i]) * qs);
    ob.u[i] = f2bf((x2 * cc[i] + x1 * ss[i]) * qs);
  }
  *(uint64_t*)(p + c) = oa.q;
  *(uint64_t*)(p + 64 + c) = ob.q;
}

// ---------------------------------------------------------------- V transpose: [bh][s][d] -> [bh][d][s]
__global__ void transpose_v_k(const unsigned short* __restrict__ v,
                              unsigned short* __restrict__ vt) {
  __shared__ unsigned short tile[64][72];
  int bh = blockIdx.x, st = blockIdx.y, dt = blockIdx.z;
  const unsigned short* src = v + ((size_t)bh * 2048 + st * 64) * 128 + dt * 64;
  unsigned short* dst = vt + ((size_t)bh * 128 + dt * 64) * 2048 + st * 64;
  int t = threadIdx.x;
  int r = t >> 2, c0 = (t & 3) * 16;
  *(bf16x8*)&tile[r][c0] = *(const bf16x8*)(src + (size_t)r * 128 + c0);
  *(bf16x8*)&tile[r][c0 + 8] = *(const bf16x8*)(src + (size_t)r * 128 + c0 + 8);
  __syncthreads();
  unsigned short o[16];
#pragma unroll
  for (int i = 0; i < 16; i++) o[i] = tile[c0 + i][r];
  *(bf16x8*)(dst + (size_t)r * 2048 + c0) = *(const bf16x8*)&o[0];
  *(bf16x8*)(dst + (size_t)r * 2048 + c0 + 8) = *(const bf16x8*)&o[8];
}

// ---------------------------------------------------------------- 128-tile GEMM (m97 structure), kept for Wo
template <int EPI>
__global__ __launch_bounds__(256, 2) void gemm_bt(
    const unsigned short* __restrict__ A, const unsigned short* __restrict__ Bm,
    float* __restrict__ Cf, unsigned short* __restrict__ q_out,
    unsigned short* __restrict__ k_out, unsigned short* __restrict__ v_out,
    int M, int N, int K) {
  __shared__ unsigned short sA[128 * 32];
  __shared__ unsigned short sB[128 * 32];
  const int t = threadIdx.x;
  const int w = t >> 6, l = t & 63;
  const int wr = w >> 1, wc = w & 1;
  const int bm = blockIdx.x * 128, bn = blockIdx.y * 128;
  const int lr = l & 15, lg = l >> 4;
  f32x4 acc[4][4] = {};

  const int srow = w * 16 + (l >> 2);
  const int sseg = (l & 3) * 8;
  const unsigned short* ga = A + (size_t)(bm + srow) * K + sseg;
  const unsigned short* gb = Bm + (size_t)(bn + srow) * K + sseg;
  unsigned short* lA = sA + w * 512 + l * 8;
  unsigned short* lB = sB + w * 512 + l * 8;

  for (int kt = 0; kt < K; kt += 32) {
    __syncthreads();
    GLOAD16(ga + kt, lA);
    GLOAD16(ga + kt + (size_t)64 * K, lA + 2048);
    GLOAD16(gb + kt, lB);
    GLOAD16(gb + kt + (size_t)64 * K, lB + 2048);
    __syncthreads();
    bf16x8 af[4], bfv[4];
#pragma unroll
    for (int m = 0; m < 4; m++)
      af[m] = *(const bf16x8*)(sA + (wr * 64 + m * 16 + lr) * 32 + lg * 8);
#pragma unroll
    for (int n = 0; n < 4; n++)
      bfv[n] = *(const bf16x8*)(sB + (wc * 64 + n * 16 + lr) * 32 + lg * 8);
#pragma unroll
    for (int m = 0; m < 4; m++)
#pragma unroll
      for (int n = 0; n < 4; n++)
        acc[m][n] = __builtin_amdgcn_mfma_f32_16x16x32_bf16(af[m], bfv[n],
                                                            acc[m][n], 0, 0, 0);
  }

#pragma unroll
  for (int m = 0; m < 4; m++) {
#pragma unroll
    for (int n = 0; n < 4; n++) {
      int gm0 = bm + wr * 64 + m * 16 + lg * 4;
      int gn = bn + wc * 64 + n * 16 + lr;
#pragma unroll
      for (int j = 0; j < 4; j++) {
        float v = acc[m][n][j];
        int gm = gm0 + j;
        if (EPI == 0) {
          Cf[(size_t)gm * N + gn] = v;
        } else {
          int which = gn >> 11, rem = gn & 2047;
          int h = rem >> 7, d = rem & 127;
          int b = gm >> 11, s = gm & 2047;
          unsigned short* dst = which == 0 ? q_out : (which == 1 ? k_out : v_out);
          dst[(((size_t)(b * 16 + h)) * 2048 + s) * 128 + d] = f2bf(v);
        }
      }
    }
  }
}

// ---------------------------------------------------------------- 256x256 8-phase GEMM (m201 geometry)
// C = A(MxK) * B(NxK)^T. 512 threads = 8 waves (2M x 4N), per-wave C 128x64.
// BK=64 as two k-halves of 32. LDS planes [256][32] bf16; read granule swizzle
// g ^= (row>>1)&3 (2-way only => free); staging pre-swizzles the global source.
// Half-tile staging (2 gload_lds each): A.k0, B.k0, A.k1, B.k1 of tile t+1 at
// phases 1-4 of tile t; vmcnt(4) at end of ph2 and ph4 (never 0).
template <int EPI>
__global__ __launch_bounds__(512, 1) void gemm256(
    const unsigned short* __restrict__ A, const unsigned short* __restrict__ Bm,
    float* __restrict__ Cf, unsigned short* __restrict__ q_out,
    unsigned short* __restrict__ k_out, unsigned short* __restrict__ v_out,
    int M, int N, int K, int nbm) {
  __shared__ unsigned short sA[2][2][256 * 32];  // 64KB [dbuf][khalf]
  __shared__ unsigned short sB[2][2][256 * 32];  // 64KB [dbuf][khalf]

  const int t = threadIdx.x;
  const int w = t >> 6, l = t & 63;
  const int wr = w >> 2, wc = w & 3;  // 2M x 4N waves
  const int lr = l & 15, lg = l >> 4;
  const int gsw = (lg ^ ((lr >> 1) & 3)) * 8;  // conflict-free read granule

  const int cpx = gridDim.x >> 3;  // bijective XCD swizzle (grid % 8 == 0)
  const int bid = blockIdx.x;
  const int swz = (bid & 7) * cpx + (bid >> 3);
  const int bm = (swz % nbm) * 256, bn = (swz / nbm) * 256;

  f32x4 acc[8][4] = {};

  const unsigned short* Ab = A + (size_t)bm * K;
  const unsigned short* Bb = Bm + (size_t)bn * K;

  // one k-half plane: 256 rows x 32 k shorts = 1024 granules, 2 loads/thread
#define STAGE_H(Xb, plane, koff)                                               \
  do {                                                                         \
    _Pragma("unroll") for (int i = 0; i < 2; i++) {                            \
      int g = i * 512 + t;                                                     \
      int row = g >> 2, c = g & 3;                                             \
      GLOAD16(Xb + (size_t)row * K + (koff) + ((c ^ ((row >> 1) & 3)) * 8),    \
              (plane) + g * 8);                                                \
    }                                                                          \
  } while (0)

  // prologue: tile 0 halves in use-order Ak0, Bk0, Ak1, Bk1; vmcnt(4) => k0 ready
  STAGE_H(Ab, &sA[0][0][0], 0);
  STAGE_H(Bb, &sB[0][0][0], 0);
  STAGE_H(Ab, &sA[0][1][0], 32);
  STAGE_H(Bb, &sB[0][1][0], 32);
  asm volatile("s_waitcnt vmcnt(4)" ::: "memory");
  __builtin_amdgcn_s_barrier();

  const int NT = K >> 6;  // K-tiles of 64
  for (int t2 = 0; t2 < NT; ++t2) {
    const int db = t2 & 1, dn = db ^ 1;
    const int kt = (t2 + 1 < NT ? t2 + 1 : t2) * 64;
    bf16x8 a[4], a2[4], b[4];

    // ---- phase 1: read A.k0 m0-3 + B.k0 ; stage A.k0(t+1)
#pragma unroll
    for (int mf = 0; mf < 4; mf++)
      a[mf] = *(const bf16x8*)&sA[db][0][(wr * 128 + mf * 16 + lr) * 32 + gsw];
#pragma unroll
    for (int nf = 0; nf < 4; nf++)
      b[nf] = *(const bf16x8*)&sB[db][0][(wc * 64 + nf * 16 + lr) * 32 + gsw];
    STAGE_H(Ab, &sA[dn][0][0], kt);
    __builtin_amdgcn_s_barrier();
    asm volatile("s_waitcnt lgkmcnt(0)" ::: "memory");
    __builtin_amdgcn_sched_barrier(0);
    __builtin_amdgcn_s_setprio(1);
#pragma unroll
    for (int mf = 0; mf < 4; mf++)
#pragma unroll
      for (int nf = 0; nf < 4; nf++)
        acc[mf][nf] = __builtin_amdgcn_mfma_f32_16x16x32_bf16(a[mf], b[nf],
                                                              acc[mf][nf], 0, 0, 0);
    __builtin_amdgcn_s_setprio(0);
    __builtin_amdgcn_s_barrier();

    // ---- phase 2: read A.k0 m4-7 ; stage B.k0(t+1) ; vmcnt(4)
#pragma unroll
    for (int mf = 0; mf < 4; mf++)
      a2[mf] = *(const bf16x8*)&sA[db][0][(wr * 128 + (mf + 4) * 16 + lr) * 32 + gsw];
    STAGE_H(Bb, &sB[dn][0][0], kt);
    __builtin_amdgcn_s_barrier();
    asm volatile("s_waitcnt lgkmcnt(0)" ::: "memory");
    __builtin_amdgcn_sched_barrier(0);
    __builtin_amdgcn_s_setprio(1);
#pragma unroll
    for (int mf = 0; mf < 4; mf++)
#pragma unroll
      for (int nf = 0; nf < 4; nf++)
        acc[mf + 4][nf] = __builtin_amdgcn_mfma_f32_16x16x32_bf16(
            a2[mf], b[nf], acc[mf + 4][nf], 0, 0, 0);
    __builtin_amdgcn_s_setprio(0);
    asm volatile("s_waitcnt vmcnt(4)" ::: "memory");
    __builtin_amdgcn_s_barrier();

    // ---- phase 3: read A.k1 m0-3 + B.k1 ; stage A.k1(t+1)
#pragma unroll
    for (int mf = 0; mf < 4; mf++)
      a[mf] = *(const bf16x8*)&sA[db][1][(wr * 128 + mf * 16 + lr) * 32 + gsw];
#pragma unroll
    for (int nf = 0; nf < 4; nf++)
      b[nf] = *(const bf16x8*)&sB[db][1][(wc * 64 + nf * 16 + lr) * 32 + gsw];
    STAGE_H(Ab, &sA[dn][1][0], kt + 32);
    __builtin_amdgcn_s_barrier();
    asm volatile("s_waitcnt lgkmcnt(0)" ::: "memory");
    __builtin_amdgcn_sched_barrier(0);
    __builtin_amdgcn_s_setprio(1);
#pragma unroll
    for (int mf = 0; mf < 4; mf++)
#pragma unroll
      for (int nf = 0; nf < 4; nf++)
        acc[mf][nf] = __builtin_amdgcn_mfma_f32_16x16x32_bf16(a[mf], b[nf],
                                                              acc[mf][nf], 0, 0, 0);
    __builtin_amdgcn_s_setprio(0);
    __builtin_amdgcn_s_barrier();

    // ---- phase 4: read A.k1 m4-7 ; stage B.k1(t+1) ; vmcnt(4)
#pragma unroll
    for (int mf = 0; mf < 4; mf++)
      a2[mf] = *(const bf16x8*)&sA[db][1][(wr * 128 + (mf + 4) * 16 + lr) * 32 + gsw];
    STAGE_H(Bb, &sB[dn][1][0], kt + 32);
    __builtin_amdgcn_s_barrier();
    asm volatile("s_waitcnt lgkmcnt(0)" ::: "memory");
    __builtin_amdgcn_sched_barrier(0);
    __builtin_amdgcn_s_setprio(1);
#pragma unroll
    for (int mf = 0; mf < 4; mf++)
#pragma unroll
      for (int nf = 0; nf < 4; nf++)
        acc[mf + 4][nf] = __builtin_amdgcn_mfma_f32_16x16x32_bf16(
            a2[mf], b[nf], acc[mf + 4][nf], 0, 0, 0);
    __builtin_amdgcn_s_setprio(0);
    asm volatile("s_waitcnt vmcnt(4)" ::: "memory");
    __builtin_amdgcn_s_barrier();
  }

  // epilogue
#pragma unroll
  for (int mf = 0; mf < 8; mf++) {
#pragma unroll
    for (int nf = 0; nf < 4; nf++) {
      int gm0 = bm + wr * 128 + mf * 16 + lg * 4;
      int gn = bn + wc * 64 + nf * 16 + lr;
#pragma unroll
      for (int j = 0; j < 4; j++) {
        float v = acc[mf][nf][j];
        int gm = gm0 + j;
        if (EPI == 0) {
          Cf[(size_t)gm * N + gn] = v;
        } else {
          int which = gn >> 11, rem = gn & 2047;
          int h = rem >> 7, d = rem & 127;
          int b = gm >> 11, s = gm & 2047;
          unsigned short* dst = which == 0 ? q_out : (which == 1 ? k_out : v_out);
          dst[(((size_t)(b * 16 + h)) * 2048 + s) * 128 + d] = f2bf(v);
        }
      }
    }
  }
}

// ---------------------------------------------------------------- flash attention (32x32 MFMA)
__global__ __launch_bounds__(256, 2) void attn_k(
    const unsigned short* __restrict__ Q, const unsigned short* __restrict__ K,
    const unsigned short* __restrict__ Vt, unsigned short* __restrict__ ctx) {
  __shared__ unsigned short sK[2][64 * 128];  // 2 x 16KB
  __shared__ unsigned short sV[2][128 * 64];  // 2 x 16KB

  const int qt = blockIdx.x, bh = blockIdx.y;
  const int t = threadIdx.x;
  const int w = t >> 6, l = t & 63;
  const int lq = l & 31;   // q-row (QK) / d-col (PV)
  const int h5 = l >> 5;   // half-wave select
  const int b = bh >> 4, hh = bh & 15;
  const int q0 = qt * 128 + w * 32;
  const unsigned short* Qp = Q + ((size_t)bh * 2048 + q0) * 128;
  const unsigned short* Kbh = K + (size_t)bh * 2048 * 128;
  const unsigned short* Vbh = Vt + (size_t)bh * 128 * 2048;

  int gko[4], gvo[4];
#pragma unroll
  for (int i = 0; i < 4; i++) {
    int p = i * 256 + t;
    int rK = p >> 4, cK = p & 15;
    gko[i] = rK * 128 + ((cK ^ (rK & 7)) * 8);
    int rV = p >> 3, cV = p & 7;
    gvo[i] = rV * 2048 + ((cV ^ (rV & 7)) * 8);
  }

  bf16x8 qf[8];
#pragma unroll
  for (int st = 0; st < 8; st++)
    qf[st] = *(const bf16x8*)(Qp + lq * 128 + st * 16 + h5 * 8);

  f32x16 o[4];
#pragma unroll
  for (int db = 0; db < 4; db++) o[db] = (f32x16)0.0f;
  float m_r = -1e30f, l_r = 0.0f;

#define STAGE_KV(buf, kv)                                                      \
  do {                                                                         \
    _Pragma("unroll") for (int i = 0; i < 4; i++)                              \
        GLOAD16(Kbh + (size_t)(kv)*128 + gko[i],                               \
                sK[buf] + (i * 256 + t) * 8);                                  \
    _Pragma("unroll") for (int i = 0; i < 4; i++)                              \
        GLOAD16(Vbh + (size_t)(kv) + gvo[i], sV[buf] + (i * 256 + t) * 8);     \
  } while (0)

  STAGE_KV(0, 0);
  __syncthreads();

  for (int it = 0; it < 32; ++it) {
    const int cur = it & 1;
    if (it < 31) STAGE_KV(cur ^ 1, (it + 1) * 64);

    const char* kbuf = (const char*)sK[cur];
    const char* vbuf = (const char*)sV[cur];

    f32x16 s2[2];
#pragma unroll
    for (int kb2 = 0; kb2 < 2; kb2++) {
      s2[kb2] = (f32x16)0.0f;
      const int rr = kb2 * 32 + lq;
      const int swzz = (rr & 7) << 4;
#pragma unroll
      for (int st = 0; st < 8; st++) {
        bf16x8 kf = *(const bf16x8*)(kbuf + rr * 256 + ((st * 32 + h5 * 16) ^ swzz));
        s2[kb2] = __builtin_amdgcn_mfma_f32_32x32x16_bf16(kf, qf[st], s2[kb2], 0, 0, 0);
      }
    }

    float sm[32];
#pragma unroll
    for (int kb2 = 0; kb2 < 2; kb2++)
#pragma unroll
      for (int r = 0; r < 16; r++) sm[kb2 * 16 + r] = s2[kb2][r];

    float tmax = sm[0];
#pragma unroll
    for (int i = 1; i < 32; i++) tmax = fmaxf(tmax, sm[i]);
    tmax = fmaxf(tmax, __shfl_xor(tmax, 32));

    if (!__all(tmax <= m_r + 8.0f)) {
      float m_new = fmaxf(m_r, tmax);
      float fac = exp2f(m_r - m_new);
      l_r *= fac;
      float fo[16];
#pragma unroll
      for (int r = 0; r < 16; r++)
        fo[r] = __shfl(fac, (r & 3) + 8 * (r >> 2) + 4 * h5);
#pragma unroll
      for (int db = 0; db < 4; db++)
#pragma unroll
        for (int r = 0; r < 16; r++) o[db][r] *= fo[r];
      m_r = m_new;
    }

    float psum = 0.0f;
#pragma unroll
    for (int i = 0; i < 32; i++) {
      sm[i] = exp2f(sm[i] - m_r);
      psum += sm[i];
    }
    psum += __shfl_xor(psum, 32);
    l_r += psum;

    uint32_t wAp[2][4], wBp[2][4];
#pragma unroll
    for (int kb2 = 0; kb2 < 2; kb2++)
#pragma unroll
      for (int rq = 0; rq < 4; rq++) {
        wAp[kb2][rq] = cvt_pk_bf16(sm[kb2 * 16 + rq * 4 + 0], sm[kb2 * 16 + rq * 4 + 1]);
        wBp[kb2][rq] = cvt_pk_bf16(sm[kb2 * 16 + rq * 4 + 2], sm[kb2 * 16 + rq * 4 + 3]);
      }

#pragma unroll
    for (int st = 0; st < 4; st++) {
      const int kb2 = st >> 1, p2 = (st & 1) * 2;
      uint32_t keepA = h5 ? wAp[kb2][p2 + 1] : wAp[kb2][p2];
      uint32_t keepB = h5 ? wBp[kb2][p2 + 1] : wBp[kb2][p2];
      uint32_t sendA = h5 ? wAp[kb2][p2] : wAp[kb2][p2 + 1];
      uint32_t sendB = h5 ? wBp[kb2][p2] : wBp[kb2][p2 + 1];
      uint32_t partA = __shfl_xor(sendA, 32);
      uint32_t partB = __shfl_xor(sendB, 32);
      union {
        uint32_t u[4];
        bf16x8 v;
      } pu;
      pu.u[0] = h5 ? partA : keepA;
      pu.u[1] = h5 ? partB : keepB;
      pu.u[2] = h5 ? keepA : partA;
      pu.u[3] = h5 ? keepB : partB;
#pragma unroll
      for (int db = 0; db < 4; db++) {
        const int rv = db * 32 + lq;
        const int swzz = (rv & 7) << 4;
        bf16x8 vb = *(const bf16x8*)(vbuf + rv * 128 + ((st * 32 + h5 * 16) ^ swzz));
        o[db] = __builtin_amdgcn_mfma_f32_32x32x16_bf16(pu.v, vb, o[db], 0, 0, 0);
      }
    }
    __syncthreads();
  }

  float inv = 1.0f / l_r;
  float io[16];
#pragma unroll
  for (int r = 0; r < 16; r++)
    io[r] = __shfl(inv, (r & 3) + 8 * (r >> 2) + 4 * h5);
#pragma unroll
  for (int db = 0; db < 4; db++) {
#pragma unroll
    for (int r = 0; r < 16; r++) {
      int s = q0 + (r & 3) + 8 * (r >> 2) + 4 * h5;
      ctx[((size_t)(b * 2048 + s)) * 2048 + hh * 128 + db * 32 + lq] =
          f2bf(o[db][r] * io[r]);
    }
  }
}

// ---------------------------------------------------------------- launch
extern "C" void kernel_launch(void* const* d_in, const int* in_sizes, int n_in,
                              void* d_out, int out_size, void* d_ws,
                              size_t ws_size, hipStream_t stream) {
  const float* x = (const float*)d_in[0];
  const float* Wq = (const float*)d_in[1];
  const float* Wk = (const float*)d_in[2];
  const float* Wv = (const float*)d_in[3];
  const float* Wo = (const float*)d_in[4];
  float* out = (float*)d_out;

  const size_t BS = 4096;  // B*S
  const size_t D = 2048;

  char* p = (char*)d_ws;
  unsigned short* xb = (unsigned short*)p;   p += BS * D * 2;
  unsigned short* wqkv = (unsigned short*)p; p += 3 * D * D * 2;
  unsigned short* wo = (unsigned short*)p;   p += D * D * 2;
  unsigned short* qb = (unsigned short*)p;   p += BS * D * 2;
  unsigned short* kb = (unsigned short*)p;   p += BS * D * 2;
  unsigned short* vb = (unsigned short*)p;   p += BS * D * 2;
  float* ctab = (float*)p;                   p += 2048 * 64 * 4;
  float* stab = (float*)p;                   p += 2048 * 64 * 4;
  unsigned short* vt = wqkv;  // reuse (dead after gemm_qkv)
  unsigned short* ctx = xb;   // reuse (dead after gemm_qkv)

  // fused convert: 25,165,824 elems / 4 per thread / 256 per block
  cvt_all<<<24576, 256, 0, stream>>>(x, Wq, Wk, Wv, Wo, xb, wqkv, wo);
  rope_table_k<<<512, 256, 0, stream>>>(ctab, stab);

  // QKV projection: M=4096 (16 tiles), N=6144 (24 tiles) -> 384 blocks of 256^2
  gemm256<1><<<384, 512, 0, stream>>>(xb, wqkv, nullptr, qb, kb, vb, 4096, 6144,
                                      2048, 16);
  rope_apply_k<<<8192, 256, 0, stream>>>(qb, kb, ctab, stab);
  transpose_v_k<<<dim3(32, 32, 2), 256, 0, stream>>>(vb, vt);
  attn_k<<<dim3(16, 32), 256, 0, stream>>>(qb, kb, vt, ctx);
  gemm_bt<0><<<dim3(32, 16), 256, 0, stream>>>(ctx, wo, out, nullptr, nullptr,
                                               nullptr, 4096, 2048, 2048);
}

// Round 7
// 314.401 us; speedup vs baseline: 1.0799x; 1.0799x over previous
//
#include <hip/hip_runtime.h>
#include <cstdint>

typedef __attribute__((ext_vector_type(8))) short bf16x8;
typedef __attribute__((ext_vector_type(4))) float f32x4;
typedef __attribute__((ext_vector_type(16))) float f32x16;

__device__ inline unsigned short f2bf(float f) {
  uint32_t u = __float_as_uint(f);
  uint32_t lsb = (u >> 16) & 1u;
  u += 0x7fffu + lsb;
  return (unsigned short)(u >> 16);
}
__device__ inline float bf2f(unsigned short b) {
  return __uint_as_float(((uint32_t)b) << 16);
}
__device__ inline uint32_t cvt_pk_bf16(float lo, float hi) {
  uint32_t r;
  asm volatile("v_cvt_pk_bf16_f32 %0, %1, %2" : "=v"(r) : "v"(lo), "v"(hi));
  return r;
}

#define GLOAD16(gp, lp)                                                        \
  __builtin_amdgcn_global_load_lds(                                            \
      (const __attribute__((address_space(1))) void*)(gp),                     \
      (__attribute__((address_space(3))) void*)(lp), 16, 0, 0)

// ---------------------------------------------------------------- fused f32->bf16 convert
__global__ void cvt_all(const float* __restrict__ x, const float* __restrict__ wq,
                        const float* __restrict__ wk, const float* __restrict__ wv,
                        const float* __restrict__ wos, unsigned short* __restrict__ xb,
                        unsigned short* __restrict__ wqkv,
                        unsigned short* __restrict__ wo) {
  size_t e = ((size_t)blockIdx.x * 256 + threadIdx.x) * 4;
  const float* src;
  unsigned short* dst;
  if (e < 8388608) {
    src = x + e;
    dst = xb + e;
  } else {
    size_t r = e - 8388608;
    int k = (int)(r >> 22);
    size_t off = r & 4194303;
    if (k == 0) { src = wq + off; dst = wqkv + r; }
    else if (k == 1) { src = wk + off; dst = wqkv + r; }
    else if (k == 2) { src = wv + off; dst = wqkv + r; }
    else { src = wos + off; dst = wo + off; }
  }
  float4 v = *(const float4*)src;
  unsigned short o[4] = {f2bf(v.x), f2bf(v.y), f2bf(v.z), f2bf(v.w)};
  *(uint64_t*)dst = *(const uint64_t*)o;
}

// ---------------------------------------------------------------- rope table
__global__ void rope_table_k(float* __restrict__ ctab, float* __restrict__ stab) {
  int i = blockIdx.x * 256 + threadIdx.x;  // 2048*64 entries
  int s = i >> 6, j = i & 63;
  float invf = expf(-(float)j * (9.210340371976184f / 64.0f));
  float ang = (float)s * invf;
  ctab[i] = cosf(ang);
  stab[i] = sinf(ang);
}

// ---------------------------------------------------------------- rope apply (in-place, vectorized x4)
__global__ void rope_apply_k(unsigned short* __restrict__ qb,
                             unsigned short* __restrict__ kb,
                             const float* __restrict__ ctab,
                             const float* __restrict__ stab) {
  int row = blockIdx.x * 16 + (threadIdx.x >> 4);
  int c = (threadIdx.x & 15) * 4;
  int s = row & 2047;
  int bh = (row >> 11) & 31;
  int isK = row >> 16;
  unsigned short* base = isK ? kb : qb;
  float qs = isK ? 1.0f : (0.08838834764831845f * 1.4426950408889634f);
  unsigned short* p = base + ((size_t)bh * 2048 + s) * 128;
  float4 cv = *(const float4*)(ctab + s * 64 + c);
  float4 sv = *(const float4*)(stab + s * 64 + c);
  union { unsigned short u[4]; uint64_t q; } a, b2, oa, ob;
  a.q = *(const uint64_t*)(p + c);
  b2.q = *(const uint64_t*)(p + 64 + c);
  float cc[4] = {cv.x, cv.y, cv.z, cv.w};
  float ss[4] = {sv.x, sv.y, sv.z, sv.w};
#pragma unroll
  for (int i = 0; i < 4; i++) {
    float x1 = bf2f(a.u[i]), x2 = bf2f(b2.u[i]);
    oa.u[i] = f2bf((x1 * cc[i] - x2 * ss[i]) * qs);
    ob.u[i] = f2bf((x2 * cc[i] + x1 * ss[i]) * qs);
  }
  *(uint64_t*)(p + c) = oa.q;
  *(uint64_t*)(p + 64 + c) = ob.q;
}

// ---------------------------------------------------------------- 128-tile GEMM (m97 structure), kept for Wo
template <int EPI>
__global__ __launch_bounds__(256, 2) void gemm_bt(
    const unsigned short* __restrict__ A, const unsigned short* __restrict__ Bm,
    float* __restrict__ Cf, unsigned short* __restrict__ q_out,
    unsigned short* __restrict__ k_out, unsigned short* __restrict__ v_out,
    int M, int N, int K) {
  __shared__ unsigned short sA[128 * 32];
  __shared__ unsigned short sB[128 * 32];
  const int t = threadIdx.x;
  const int w = t >> 6, l = t & 63;
  const int wr = w >> 1, wc = w & 1;
  const int bm = blockIdx.x * 128, bn = blockIdx.y * 128;
  const int lr = l & 15, lg = l >> 4;
  f32x4 acc[4][4] = {};

  const int srow = w * 16 + (l >> 2);
  const int sseg = (l & 3) * 8;
  const unsigned short* ga = A + (size_t)(bm + srow) * K + sseg;
  const unsigned short* gb = Bm + (size_t)(bn + srow) * K + sseg;
  unsigned short* lA = sA + w * 512 + l * 8;
  unsigned short* lB = sB + w * 512 + l * 8;

  for (int kt = 0; kt < K; kt += 32) {
    __syncthreads();
    GLOAD16(ga + kt, lA);
    GLOAD16(ga + kt + (size_t)64 * K, lA + 2048);
    GLOAD16(gb + kt, lB);
    GLOAD16(gb + kt + (size_t)64 * K, lB + 2048);
    __syncthreads();
    bf16x8 af[4], bfv[4];
#pragma unroll
    for (int m = 0; m < 4; m++)
      af[m] = *(const bf16x8*)(sA + (wr * 64 + m * 16 + lr) * 32 + lg * 8);
#pragma unroll
    for (int n = 0; n < 4; n++)
      bfv[n] = *(const bf16x8*)(sB + (wc * 64 + n * 16 + lr) * 32 + lg * 8);
#pragma unroll
    for (int m = 0; m < 4; m++)
#pragma unroll
      for (int n = 0; n < 4; n++)
        acc[m][n] = __builtin_amdgcn_mfma_f32_16x16x32_bf16(af[m], bfv[n],
                                                            acc[m][n], 0, 0, 0);
  }

#pragma unroll
  for (int m = 0; m < 4; m++) {
#pragma unroll
    for (int n = 0; n < 4; n++) {
      int gm0 = bm + wr * 64 + m * 16 + lg * 4;
      int gn = bn + wc * 64 + n * 16 + lr;
#pragma unroll
      for (int j = 0; j < 4; j++) {
        float v = acc[m][n][j];
        int gm = gm0 + j;
        if (EPI == 0) {
          Cf[(size_t)gm * N + gn] = v;
        }
      }
    }
  }
}

// ---------------------------------------------------------------- 256x192 8-phase GEMM (r5-proven schedule)
// C = A(MxK) * B(NxK)^T. 512 threads = 8 waves (2M x 4N), per-wave C 128x48.
// BK=64 as two K-halves of 32. Read granule swizzle g ^= (row>>1)&3 (2-way = free).
// Stage order per K-tile: B(full,3), A.k0(2), A.k1(2); vmcnt(5)@ph2, vmcnt(2)@ph4.
// EPI 1: scatter Q,K [bh][s][d]; V written TRANSPOSED [bh][d][s] (fuses transpose_v).
template <int EPI>
__global__ __launch_bounds__(512, 1) void gemm256(
    const unsigned short* __restrict__ A, const unsigned short* __restrict__ Bm,
    float* __restrict__ Cf, unsigned short* __restrict__ q_out,
    unsigned short* __restrict__ k_out, unsigned short* __restrict__ v_out,
    int M, int N, int K, int nbm) {
  __shared__ unsigned short sA[2][2][256 * 32];  // 64KB [dbuf][khalf]
  __shared__ unsigned short sB[2][2][192 * 32];  // 48KB [dbuf][khalf]

  const int t = threadIdx.x;
  const int w = t >> 6, l = t & 63;
  const int wr = w >> 2, wc = w & 3;  // 2M x 4N waves
  const int lr = l & 15, lg = l >> 4;
  const int gsw = (lg ^ ((lr >> 1) & 3)) * 8;  // conflict-free read granule

  const int cpx = gridDim.x >> 3;  // bijective XCD swizzle (grid % 8 == 0)
  const int bid = blockIdx.x;
  const int swz = (bid & 7) * cpx + (bid >> 3);
  const int bm = (swz % nbm) * 256, bn = (swz / nbm) * 192;

  f32x4 acc[8][3] = {};

  const unsigned short* Ab = A + (size_t)bm * K;
  const unsigned short* Bb = Bm + (size_t)bn * K;

#define STAGE_A(plane, koff)                                                   \
  do {                                                                         \
    _Pragma("unroll") for (int i = 0; i < 2; i++) {                            \
      int g = i * 512 + t;                                                     \
      int row = g >> 2, c = g & 3;                                             \
      GLOAD16(Ab + (size_t)row * K + (koff) + ((c ^ ((row >> 1) & 3)) * 8),    \
              (plane) + g * 8);                                                \
    }                                                                          \
  } while (0)

#define STAGE_B(plane, koff)                                                   \
  do {                                                                         \
    _Pragma("unroll") for (int i = 0; i < 3; i++) {                            \
      int g = i * 512 + t;                                                     \
      int kh = (g >= 768) ? 1 : 0;                                             \
      int gr = g - kh * 768;                                                   \
      int row = gr >> 2, c = gr & 3;                                           \
      GLOAD16(Bb + (size_t)row * K + (koff) + kh * 32 +                        \
                  ((c ^ ((row >> 1) & 3)) * 8),                                \
              (plane) + g * 8);                                                \
    }                                                                          \
  } while (0)

  // prologue: tile 0 (B, A.k0, A.k1) = 7 loads; need B+A.k0 -> vmcnt(2)
  STAGE_B(&sB[0][0][0], 0);
  STAGE_A(&sA[0][0][0], 0);
  STAGE_A(&sA[0][1][0], 32);
  asm volatile("s_waitcnt vmcnt(2)" ::: "memory");
  __builtin_amdgcn_s_barrier();

  const int NT = K >> 6;  // K-tiles of 64
  for (int t2 = 0; t2 < NT; ++t2) {
    const int db = t2 & 1, dn = db ^ 1;
    const int kt = (t2 + 1 < NT ? t2 + 1 : t2) * 64;
    bf16x8 a[4], a2[4], b[3];

    // ---- phase 1: read A.k0 m0-3 + B.k0 ; stage B(t+1)
#pragma unroll
    for (int mf = 0; mf < 4; mf++)
      a[mf] = *(const bf16x8*)&sA[db][0][(wr * 128 + mf * 16 + lr) * 32 + gsw];
#pragma unroll
    for (int nf = 0; nf < 3; nf++)
      b[nf] = *(const bf16x8*)&sB[db][0][(wc * 48 + nf * 16 + lr) * 32 + gsw];
    STAGE_B(&sB[dn][0][0], kt);
    __builtin_amdgcn_s_barrier();
    asm volatile("s_waitcnt lgkmcnt(0)" ::: "memory");
    __builtin_amdgcn_sched_barrier(0);
    __builtin_amdgcn_s_setprio(1);
#pragma unroll
    for (int mf = 0; mf < 4; mf++)
#pragma unroll
      for (int nf = 0; nf < 3; nf++)
        acc[mf][nf] = __builtin_amdgcn_mfma_f32_16x16x32_bf16(a[mf], b[nf],
                                                              acc[mf][nf], 0, 0, 0);
    __builtin_amdgcn_s_setprio(0);
    __builtin_amdgcn_s_barrier();

    // ---- phase 2: read A.k0 m4-7 ; stage A.k0(t+1) ; vmcnt(5)
#pragma unroll
    for (int mf = 0; mf < 4; mf++)
      a2[mf] = *(const bf16x8*)&sA[db][0][(wr * 128 + (mf + 4) * 16 + lr) * 32 + gsw];
    STAGE_A(&sA[dn][0][0], kt);
    __builtin_amdgcn_s_barrier();
    asm volatile("s_waitcnt lgkmcnt(0)" ::: "memory");
    __builtin_amdgcn_sched_barrier(0);
    __builtin_amdgcn_s_setprio(1);
#pragma unroll
    for (int mf = 0; mf < 4; mf++)
#pragma unroll
      for (int nf = 0; nf < 3; nf++)
        acc[mf + 4][nf] = __builtin_amdgcn_mfma_f32_16x16x32_bf16(
            a2[mf], b[nf], acc[mf + 4][nf], 0, 0, 0);
    __builtin_amdgcn_s_setprio(0);
    asm volatile("s_waitcnt vmcnt(5)" ::: "memory");
    __builtin_amdgcn_s_barrier();

    // ---- phase 3: read A.k1 m0-3 + B.k1 ; stage A.k1(t+1)
#pragma unroll
    for (int mf = 0; mf < 4; mf++)
      a[mf] = *(const bf16x8*)&sA[db][1][(wr * 128 + mf * 16 + lr) * 32 + gsw];
#pragma unroll
    for (int nf = 0; nf < 3; nf++)
      b[nf] = *(const bf16x8*)&sB[db][1][(wc * 48 + nf * 16 + lr) * 32 + gsw];
    STAGE_A(&sA[dn][1][0], kt + 32);
    __builtin_amdgcn_s_barrier();
    asm volatile("s_waitcnt lgkmcnt(0)" ::: "memory");
    __builtin_amdgcn_sched_barrier(0);
    __builtin_amdgcn_s_setprio(1);
#pragma unroll
    for (int mf = 0; mf < 4; mf++)
#pragma unroll
      for (int nf = 0; nf < 3; nf++)
        acc[mf][nf] = __builtin_amdgcn_mfma_f32_16x16x32_bf16(a[mf], b[nf],
                                                              acc[mf][nf], 0, 0, 0);
    __builtin_amdgcn_s_setprio(0);
    __builtin_amdgcn_s_barrier();

    // ---- phase 4: read A.k1 m4-7 ; no stage ; vmcnt(2)
#pragma unroll
    for (int mf = 0; mf < 4; mf++)
      a2[mf] = *(const bf16x8*)&sA[db][1][(wr * 128 + (mf + 4) * 16 + lr) * 32 + gsw];
    __builtin_amdgcn_s_barrier();
    asm volatile("s_waitcnt lgkmcnt(0)" ::: "memory");
    __builtin_amdgcn_sched_barrier(0);
    __builtin_amdgcn_s_setprio(1);
#pragma unroll
    for (int mf = 0; mf < 4; mf++)
#pragma unroll
      for (int nf = 0; nf < 3; nf++)
        acc[mf + 4][nf] = __builtin_amdgcn_mfma_f32_16x16x32_bf16(
            a2[mf], b[nf], acc[mf + 4][nf], 0, 0, 0);
    __builtin_amdgcn_s_setprio(0);
    asm volatile("s_waitcnt vmcnt(2)" ::: "memory");
    __builtin_amdgcn_s_barrier();
  }

  // epilogue
#pragma unroll
  for (int mf = 0; mf < 8; mf++) {
#pragma unroll
    for (int nf = 0; nf < 3; nf++) {
      int gm0 = bm + wr * 128 + mf * 16 + lg * 4;
      int gn = bn + wc * 48 + nf * 16 + lr;
#pragma unroll
      for (int j = 0; j < 4; j++) {
        float v = acc[mf][nf][j];
        int gm = gm0 + j;
        if (EPI == 0) {
          Cf[(size_t)gm * N + gn] = v;
        } else {
          int which = gn >> 11, rem = gn & 2047;
          int h = rem >> 7, d = rem & 127;
          int b = gm >> 11, s = gm & 2047;
          if (which == 2) {
            // V transposed: [bh][d][s]  (fused transpose_v)
            v_out[(((size_t)(b * 16 + h)) * 128 + d) * 2048 + s] = f2bf(v);
          } else {
            unsigned short* dst = which == 0 ? q_out : k_out;
            dst[(((size_t)(b * 16 + h)) * 2048 + s) * 128 + d] = f2bf(v);
          }
        }
      }
    }
  }
}

// ---------------------------------------------------------------- flash attention (32x32 MFMA)
__global__ __launch_bounds__(256, 2) void attn_k(
    const unsigned short* __restrict__ Q, const unsigned short* __restrict__ K,
    const unsigned short* __restrict__ Vt, unsigned short* __restrict__ ctx) {
  __shared__ unsigned short sK[2][64 * 128];  // 2 x 16KB
  __shared__ unsigned short sV[2][128 * 64];  // 2 x 16KB

  const int qt = blockIdx.x, bh = blockIdx.y;
  const int t = threadIdx.x;
  const int w = t >> 6, l = t & 63;
  const int lq = l & 31;   // q-row (QK) / d-col (PV)
  const int h5 = l >> 5;   // half-wave select
  const int b = bh >> 4, hh = bh & 15;
  const int q0 = qt * 128 + w * 32;
  const unsigned short* Qp = Q + ((size_t)bh * 2048 + q0) * 128;
  const unsigned short* Kbh = K + (size_t)bh * 2048 * 128;
  const unsigned short* Vbh = Vt + (size_t)bh * 128 * 2048;

  int gko[4], gvo[4];
#pragma unroll
  for (int i = 0; i < 4; i++) {
    int p = i * 256 + t;
    int rK = p >> 4, cK = p & 15;
    gko[i] = rK * 128 + ((cK ^ (rK & 7)) * 8);
    int rV = p >> 3, cV = p & 7;
    gvo[i] = rV * 2048 + ((cV ^ (rV & 7)) * 8);
  }

  bf16x8 qf[8];
#pragma unroll
  for (int st = 0; st < 8; st++)
    qf[st] = *(const bf16x8*)(Qp + lq * 128 + st * 16 + h5 * 8);

  f32x16 o[4];
#pragma unroll
  for (int db = 0; db < 4; db++) o[db] = (f32x16)0.0f;
  float m_r = -1e30f, l_r = 0.0f;

#define STAGE_KV(buf, kv)                                                      \
  do {                                                                         \
    _Pragma("unroll") for (int i = 0; i < 4; i++)                              \
        GLOAD16(Kbh + (size_t)(kv)*128 + gko[i],                               \
                sK[buf] + (i * 256 + t) * 8);                                  \
    _Pragma("unroll") for (int i = 0; i < 4; i++)                              \
        GLOAD16(Vbh + (size_t)(kv) + gvo[i], sV[buf] + (i * 256 + t) * 8);     \
  } while (0)

  STAGE_KV(0, 0);
  __syncthreads();

  for (int it = 0; it < 32; ++it) {
    const int cur = it & 1;
    if (it < 31) STAGE_KV(cur ^ 1, (it + 1) * 64);

    const char* kbuf = (const char*)sK[cur];
    const char* vbuf = (const char*)sV[cur];

    f32x16 s2[2];
#pragma unroll
    for (int kb2 = 0; kb2 < 2; kb2++) {
      s2[kb2] = (f32x16)0.0f;
      const int rr = kb2 * 32 + lq;
      const int swzz = (rr & 7) << 4;
#pragma unroll
      for (int st = 0; st < 8; st++) {
        bf16x8 kf = *(const bf16x8*)(kbuf + rr * 256 + ((st * 32 + h5 * 16) ^ swzz));
        s2[kb2] = __builtin_amdgcn_mfma_f32_32x32x16_bf16(kf, qf[st], s2[kb2], 0, 0, 0);
      }
    }

    float sm[32];
#pragma unroll
    for (int kb2 = 0; kb2 < 2; kb2++)
#pragma unroll
      for (int r = 0; r < 16; r++) sm[kb2 * 16 + r] = s2[kb2][r];

    float tmax = sm[0];
#pragma unroll
    for (int i = 1; i < 32; i++) tmax = fmaxf(tmax, sm[i]);
    tmax = fmaxf(tmax, __shfl_xor(tmax, 32));

    if (!__all(tmax <= m_r + 8.0f)) {
      float m_new = fmaxf(m_r, tmax);
      float fac = exp2f(m_r - m_new);
      l_r *= fac;
      float fo[16];
#pragma unroll
      for (int r = 0; r < 16; r++)
        fo[r] = __shfl(fac, (r & 3) + 8 * (r >> 2) + 4 * h5);
#pragma unroll
      for (int db = 0; db < 4; db++)
#pragma unroll
        for (int r = 0; r < 16; r++) o[db][r] *= fo[r];
      m_r = m_new;
    }

    float psum = 0.0f;
#pragma unroll
    for (int i = 0; i < 32; i++) {
      sm[i] = exp2f(sm[i] - m_r);
      psum += sm[i];
    }
    psum += __shfl_xor(psum, 32);
    l_r += psum;

    uint32_t wAp[2][4], wBp[2][4];
#pragma unroll
    for (int kb2 = 0; kb2 < 2; kb2++)
#pragma unroll
      for (int rq = 0; rq < 4; rq++) {
        wAp[kb2][rq] = cvt_pk_bf16(sm[kb2 * 16 + rq * 4 + 0], sm[kb2 * 16 + rq * 4 + 1]);
        wBp[kb2][rq] = cvt_pk_bf16(sm[kb2 * 16 + rq * 4 + 2], sm[kb2 * 16 + rq * 4 + 3]);
      }

#pragma unroll
    for (int st = 0; st < 4; st++) {
      const int kb2 = st >> 1, p2 = (st & 1) * 2;
      uint32_t keepA = h5 ? wAp[kb2][p2 + 1] : wAp[kb2][p2];
      uint32_t keepB = h5 ? wBp[kb2][p2 + 1] : wBp[kb2][p2];
      uint32_t sendA = h5 ? wAp[kb2][p2] : wAp[kb2][p2 + 1];
      uint32_t sendB = h5 ? wBp[kb2][p2] : wBp[kb2][p2 + 1];
      uint32_t partA = __shfl_xor(sendA, 32);
      uint32_t partB = __shfl_xor(sendB, 32);
      union {
        uint32_t u[4];
        bf16x8 v;
      } pu;
      pu.u[0] = h5 ? partA : keepA;
      pu.u[1] = h5 ? partB : keepB;
      pu.u[2] = h5 ? keepA : partA;
      pu.u[3] = h5 ? keepB : partB;
#pragma unroll
      for (int db = 0; db < 4; db++) {
        const int rv = db * 32 + lq;
        const int swzz = (rv & 7) << 4;
        bf16x8 vb = *(const bf16x8*)(vbuf + rv * 128 + ((st * 32 + h5 * 16) ^ swzz));
        o[db] = __builtin_amdgcn_mfma_f32_32x32x16_bf16(pu.v, vb, o[db], 0, 0, 0);
      }
    }
    __syncthreads();
  }

  float inv = 1.0f / l_r;
  float io[16];
#pragma unroll
  for (int r = 0; r < 16; r++)
    io[r] = __shfl(inv, (r & 3) + 8 * (r >> 2) + 4 * h5);
#pragma unroll
  for (int db = 0; db < 4; db++) {
#pragma unroll
    for (int r = 0; r < 16; r++) {
      int s = q0 + (r & 3) + 8 * (r >> 2) + 4 * h5;
      ctx[((size_t)(b * 2048 + s)) * 2048 + hh * 128 + db * 32 + lq] =
          f2bf(o[db][r] * io[r]);
    }
  }
}

// ---------------------------------------------------------------- launch
extern "C" void kernel_launch(void* const* d_in, const int* in_sizes, int n_in,
                              void* d_out, int out_size, void* d_ws,
                              size_t ws_size, hipStream_t stream) {
  const float* x = (const float*)d_in[0];
  const float* Wq = (const float*)d_in[1];
  const float* Wk = (const float*)d_in[2];
  const float* Wv = (const float*)d_in[3];
  const float* Wo = (const float*)d_in[4];
  float* out = (float*)d_out;

  const size_t BS = 4096;  // B*S
  const size_t D = 2048;

  char* p = (char*)d_ws;
  unsigned short* xb = (unsigned short*)p;   p += BS * D * 2;
  unsigned short* wqkv = (unsigned short*)p; p += 3 * D * D * 2;
  unsigned short* wo = (unsigned short*)p;   p += D * D * 2;
  unsigned short* qb = (unsigned short*)p;   p += BS * D * 2;
  unsigned short* kb = (unsigned short*)p;   p += BS * D * 2;
  unsigned short* vtb = (unsigned short*)p;  p += BS * D * 2;  // V transposed [bh][d][s]
  float* ctab = (float*)p;                   p += 2048 * 64 * 4;
  float* stab = (float*)p;                   p += 2048 * 64 * 4;
  unsigned short* ctx = xb;  // reuse (dead after gemm256)

  // fused convert: 25,165,824 elems / 4 per thread / 256 per block
  cvt_all<<<24576, 256, 0, stream>>>(x, Wq, Wk, Wv, Wo, xb, wqkv, wo);
  rope_table_k<<<512, 256, 0, stream>>>(ctab, stab);

  // QKV projection: M=4096 (16 tiles of 256), N=6144 (32 tiles of 192) -> 512 blocks
  gemm256<1><<<512, 512, 0, stream>>>(xb, wqkv, nullptr, qb, kb, vtb, 4096, 6144,
                                      2048, 16);
  rope_apply_k<<<8192, 256, 0, stream>>>(qb, kb, ctab, stab);
  attn_k<<<dim3(16, 32), 256, 0, stream>>>(qb, kb, vtb, ctx);
  gemm_bt<0><<<dim3(32, 16), 256, 0, stream>>>(ctx, wo, out, nullptr, nullptr,
                                               nullptr, 4096, 2048, 2048);
}

// Round 8
// 293.103 us; speedup vs baseline: 1.1584x; 1.0727x over previous
//
#include <hip/hip_runtime.h>
#include <cstdint>

typedef __attribute__((ext_vector_type(8))) short bf16x8;
typedef __attribute__((ext_vector_type(4))) float f32x4;
typedef __attribute__((ext_vector_type(16))) float f32x16;

__device__ inline unsigned short f2bf(float f) {
  uint32_t u = __float_as_uint(f);
  uint32_t lsb = (u >> 16) & 1u;
  u += 0x7fffu + lsb;
  return (unsigned short)(u >> 16);
}
__device__ inline float bf2f(unsigned short b) {
  return __uint_as_float(((uint32_t)b) << 16);
}
__device__ inline uint32_t cvt_pk_bf16(float lo, float hi) {
  uint32_t r;
  asm volatile("v_cvt_pk_bf16_f32 %0, %1, %2" : "=v"(r) : "v"(lo), "v"(hi));
  return r;
}

#define GLOAD16(gp, lp)                                                        \
  __builtin_amdgcn_global_load_lds(                                            \
      (const __attribute__((address_space(1))) void*)(gp),                     \
      (__attribute__((address_space(3))) void*)(lp), 16, 0, 0)

// ---------------------------------------------------------------- fused f32->bf16 convert
__global__ void cvt_all(const float* __restrict__ x, const float* __restrict__ wq,
                        const float* __restrict__ wk, const float* __restrict__ wv,
                        const float* __restrict__ wos, unsigned short* __restrict__ xb,
                        unsigned short* __restrict__ wqkv,
                        unsigned short* __restrict__ wo) {
  size_t e = ((size_t)blockIdx.x * 256 + threadIdx.x) * 4;
  const float* src;
  unsigned short* dst;
  if (e < 8388608) {
    src = x + e;
    dst = xb + e;
  } else {
    size_t r = e - 8388608;
    int k = (int)(r >> 22);
    size_t off = r & 4194303;
    if (k == 0) { src = wq + off; dst = wqkv + r; }
    else if (k == 1) { src = wk + off; dst = wqkv + r; }
    else if (k == 2) { src = wv + off; dst = wqkv + r; }
    else { src = wos + off; dst = wo + off; }
  }
  float4 v = *(const float4*)src;
  unsigned short o[4] = {f2bf(v.x), f2bf(v.y), f2bf(v.z), f2bf(v.w)};
  *(uint64_t*)dst = *(const uint64_t*)o;
}

// ---------------------------------------------------------------- rope table
__global__ void rope_table_k(float* __restrict__ ctab, float* __restrict__ stab) {
  int i = blockIdx.x * 256 + threadIdx.x;  // 2048*64 entries
  int s = i >> 6, j = i & 63;
  float invf = expf(-(float)j * (9.210340371976184f / 64.0f));
  float ang = (float)s * invf;
  ctab[i] = cosf(ang);
  stab[i] = sinf(ang);
}

// ---------------------------------------------------------------- rope apply (in-place, vectorized x4)
__global__ void rope_apply_k(unsigned short* __restrict__ qb,
                             unsigned short* __restrict__ kb,
                             const float* __restrict__ ctab,
                             const float* __restrict__ stab) {
  int row = blockIdx.x * 16 + (threadIdx.x >> 4);
  int c = (threadIdx.x & 15) * 4;
  int s = row & 2047;
  int bh = (row >> 11) & 31;
  int isK = row >> 16;
  unsigned short* base = isK ? kb : qb;
  float qs = isK ? 1.0f : (0.08838834764831845f * 1.4426950408889634f);
  unsigned short* p = base + ((size_t)bh * 2048 + s) * 128;
  float4 cv = *(const float4*)(ctab + s * 64 + c);
  float4 sv = *(const float4*)(stab + s * 64 + c);
  union { unsigned short u[4]; uint64_t q; } a, b2, oa, ob;
  a.q = *(const uint64_t*)(p + c);
  b2.q = *(const uint64_t*)(p + 64 + c);
  float cc[4] = {cv.x, cv.y, cv.z, cv.w};
  float ss[4] = {sv.x, sv.y, sv.z, sv.w};
#pragma unroll
  for (int i = 0; i < 4; i++) {
    float x1 = bf2f(a.u[i]), x2 = bf2f(b2.u[i]);
    oa.u[i] = f2bf((x1 * cc[i] - x2 * ss[i]) * qs);
    ob.u[i] = f2bf((x2 * cc[i] + x1 * ss[i]) * qs);
  }
  *(uint64_t*)(p + c) = oa.q;
  *(uint64_t*)(p + 64 + c) = ob.q;
}

// ---------------------------------------------------------------- V transpose: [bh][s][d] -> [bh][d][s]
__global__ void transpose_v_k(const unsigned short* __restrict__ v,
                              unsigned short* __restrict__ vt) {
  __shared__ unsigned short tile[64][72];
  int bh = blockIdx.x, st = blockIdx.y, dt = blockIdx.z;
  const unsigned short* src = v + ((size_t)bh * 2048 + st * 64) * 128 + dt * 64;
  unsigned short* dst = vt + ((size_t)bh * 128 + dt * 64) * 2048 + st * 64;
  int t = threadIdx.x;
  int r = t >> 2, c0 = (t & 3) * 16;
  *(bf16x8*)&tile[r][c0] = *(const bf16x8*)(src + (size_t)r * 128 + c0);
  *(bf16x8*)&tile[r][c0 + 8] = *(const bf16x8*)(src + (size_t)r * 128 + c0 + 8);
  __syncthreads();
  unsigned short o[16];
#pragma unroll
  for (int i = 0; i < 16; i++) o[i] = tile[c0 + i][r];
  *(bf16x8*)(dst + (size_t)r * 2048 + c0) = *(const bf16x8*)&o[0];
  *(bf16x8*)(dst + (size_t)r * 2048 + c0 + 8) = *(const bf16x8*)&o[8];
}

// ---------------------------------------------------------------- 128-tile GEMM (m97 structure), kept for Wo
template <int EPI>
__global__ __launch_bounds__(256, 2) void gemm_bt(
    const unsigned short* __restrict__ A, const unsigned short* __restrict__ Bm,
    float* __restrict__ Cf, int M, int N, int K) {
  __shared__ unsigned short sA[128 * 32];
  __shared__ unsigned short sB[128 * 32];
  const int t = threadIdx.x;
  const int w = t >> 6, l = t & 63;
  const int wr = w >> 1, wc = w & 1;
  const int bm = blockIdx.x * 128, bn = blockIdx.y * 128;
  const int lr = l & 15, lg = l >> 4;
  f32x4 acc[4][4] = {};

  const int srow = w * 16 + (l >> 2);
  const int sseg = (l & 3) * 8;
  const unsigned short* ga = A + (size_t)(bm + srow) * K + sseg;
  const unsigned short* gb = Bm + (size_t)(bn + srow) * K + sseg;
  unsigned short* lA = sA + w * 512 + l * 8;
  unsigned short* lB = sB + w * 512 + l * 8;

  for (int kt = 0; kt < K; kt += 32) {
    __syncthreads();
    GLOAD16(ga + kt, lA);
    GLOAD16(ga + kt + (size_t)64 * K, lA + 2048);
    GLOAD16(gb + kt, lB);
    GLOAD16(gb + kt + (size_t)64 * K, lB + 2048);
    __syncthreads();
    bf16x8 af[4], bfv[4];
#pragma unroll
    for (int m = 0; m < 4; m++)
      af[m] = *(const bf16x8*)(sA + (wr * 64 + m * 16 + lr) * 32 + lg * 8);
#pragma unroll
    for (int n = 0; n < 4; n++)
      bfv[n] = *(const bf16x8*)(sB + (wc * 64 + n * 16 + lr) * 32 + lg * 8);
#pragma unroll
    for (int m = 0; m < 4; m++)
#pragma unroll
      for (int n = 0; n < 4; n++)
        acc[m][n] = __builtin_amdgcn_mfma_f32_16x16x32_bf16(af[m], bfv[n],
                                                            acc[m][n], 0, 0, 0);
  }

#pragma unroll
  for (int m = 0; m < 4; m++) {
#pragma unroll
    for (int n = 0; n < 4; n++) {
      int gm0 = bm + wr * 64 + m * 16 + lg * 4;
      int gn = bn + wc * 64 + n * 16 + lr;
#pragma unroll
      for (int j = 0; j < 4; j++) {
        Cf[(size_t)(gm0 + j) * N + gn] = acc[m][n][j];
      }
    }
  }
}

// ---------------------------------------------------------------- 256x192 8-phase GEMM (r5-proven schedule)
// C = A(MxK) * B(NxK)^T. 512 threads = 8 waves (2M x 4N), per-wave C 128x48.
// BK=64 as two K-halves of 32. Read granule swizzle g ^= (row>>1)&3 (2-way = free).
// Stage order per K-tile: B(full,3), A.k0(2), A.k1(2); vmcnt(5)@ph2, vmcnt(2)@ph4.
// EPI 1: scatter Q,K,V row-major [bh][s][d] (coalesced within lr runs).
template <int EPI>
__global__ __launch_bounds__(512, 1) void gemm256(
    const unsigned short* __restrict__ A, const unsigned short* __restrict__ Bm,
    float* __restrict__ Cf, unsigned short* __restrict__ q_out,
    unsigned short* __restrict__ k_out, unsigned short* __restrict__ v_out,
    int M, int N, int K, int nbm) {
  __shared__ unsigned short sA[2][2][256 * 32];  // 64KB [dbuf][khalf]
  __shared__ unsigned short sB[2][2][192 * 32];  // 48KB [dbuf][khalf]

  const int t = threadIdx.x;
  const int w = t >> 6, l = t & 63;
  const int wr = w >> 2, wc = w & 3;  // 2M x 4N waves
  const int lr = l & 15, lg = l >> 4;
  const int gsw = (lg ^ ((lr >> 1) & 3)) * 8;  // conflict-free read granule

  const int cpx = gridDim.x >> 3;  // bijective XCD swizzle (grid % 8 == 0)
  const int bid = blockIdx.x;
  const int swz = (bid & 7) * cpx + (bid >> 3);
  const int bm = (swz % nbm) * 256, bn = (swz / nbm) * 192;

  f32x4 acc[8][3] = {};

  const unsigned short* Ab = A + (size_t)bm * K;
  const unsigned short* Bb = Bm + (size_t)bn * K;

#define STAGE_A(plane, koff)                                                   \
  do {                                                                         \
    _Pragma("unroll") for (int i = 0; i < 2; i++) {                            \
      int g = i * 512 + t;                                                     \
      int row = g >> 2, c = g & 3;                                             \
      GLOAD16(Ab + (size_t)row * K + (koff) + ((c ^ ((row >> 1) & 3)) * 8),    \
              (plane) + g * 8);                                                \
    }                                                                          \
  } while (0)

#define STAGE_B(plane, koff)                                                   \
  do {                                                                         \
    _Pragma("unroll") for (int i = 0; i < 3; i++) {                            \
      int g = i * 512 + t;                                                     \
      int kh = (g >= 768) ? 1 : 0;                                             \
      int gr = g - kh * 768;                                                   \
      int row = gr >> 2, c = gr & 3;                                           \
      GLOAD16(Bb + (size_t)row * K + (koff) + kh * 32 +                        \
                  ((c ^ ((row >> 1) & 3)) * 8),                                \
              (plane) + g * 8);                                                \
    }                                                                          \
  } while (0)

  // prologue: tile 0 (B, A.k0, A.k1) = 7 loads; need B+A.k0 -> vmcnt(2)
  STAGE_B(&sB[0][0][0], 0);
  STAGE_A(&sA[0][0][0], 0);
  STAGE_A(&sA[0][1][0], 32);
  asm volatile("s_waitcnt vmcnt(2)" ::: "memory");
  __builtin_amdgcn_s_barrier();

  const int NT = K >> 6;  // K-tiles of 64
  for (int t2 = 0; t2 < NT; ++t2) {
    const int db = t2 & 1, dn = db ^ 1;
    const int kt = (t2 + 1 < NT ? t2 + 1 : t2) * 64;
    bf16x8 a[4], a2[4], b[3];

    // ---- phase 1: read A.k0 m0-3 + B.k0 ; stage B(t+1)
#pragma unroll
    for (int mf = 0; mf < 4; mf++)
      a[mf] = *(const bf16x8*)&sA[db][0][(wr * 128 + mf * 16 + lr) * 32 + gsw];
#pragma unroll
    for (int nf = 0; nf < 3; nf++)
      b[nf] = *(const bf16x8*)&sB[db][0][(wc * 48 + nf * 16 + lr) * 32 + gsw];
    STAGE_B(&sB[dn][0][0], kt);
    __builtin_amdgcn_s_barrier();
    asm volatile("s_waitcnt lgkmcnt(0)" ::: "memory");
    __builtin_amdgcn_sched_barrier(0);
    __builtin_amdgcn_s_setprio(1);
#pragma unroll
    for (int mf = 0; mf < 4; mf++)
#pragma unroll
      for (int nf = 0; nf < 3; nf++)
        acc[mf][nf] = __builtin_amdgcn_mfma_f32_16x16x32_bf16(a[mf], b[nf],
                                                              acc[mf][nf], 0, 0, 0);
    __builtin_amdgcn_s_setprio(0);
    __builtin_amdgcn_s_barrier();

    // ---- phase 2: read A.k0 m4-7 ; stage A.k0(t+1) ; vmcnt(5)
#pragma unroll
    for (int mf = 0; mf < 4; mf++)
      a2[mf] = *(const bf16x8*)&sA[db][0][(wr * 128 + (mf + 4) * 16 + lr) * 32 + gsw];
    STAGE_A(&sA[dn][0][0], kt);
    __builtin_amdgcn_s_barrier();
    asm volatile("s_waitcnt lgkmcnt(0)" ::: "memory");
    __builtin_amdgcn_sched_barrier(0);
    __builtin_amdgcn_s_setprio(1);
#pragma unroll
    for (int mf = 0; mf < 4; mf++)
#pragma unroll
      for (int nf = 0; nf < 3; nf++)
        acc[mf + 4][nf] = __builtin_amdgcn_mfma_f32_16x16x32_bf16(
            a2[mf], b[nf], acc[mf + 4][nf], 0, 0, 0);
    __builtin_amdgcn_s_setprio(0);
    asm volatile("s_waitcnt vmcnt(5)" ::: "memory");
    __builtin_amdgcn_s_barrier();

    // ---- phase 3: read A.k1 m0-3 + B.k1 ; stage A.k1(t+1)
#pragma unroll
    for (int mf = 0; mf < 4; mf++)
      a[mf] = *(const bf16x8*)&sA[db][1][(wr * 128 + mf * 16 + lr) * 32 + gsw];
#pragma unroll
    for (int nf = 0; nf < 3; nf++)
      b[nf] = *(const bf16x8*)&sB[db][1][(wc * 48 + nf * 16 + lr) * 32 + gsw];
    STAGE_A(&sA[dn][1][0], kt + 32);
    __builtin_amdgcn_s_barrier();
    asm volatile("s_waitcnt lgkmcnt(0)" ::: "memory");
    __builtin_amdgcn_sched_barrier(0);
    __builtin_amdgcn_s_setprio(1);
#pragma unroll
    for (int mf = 0; mf < 4; mf++)
#pragma unroll
      for (int nf = 0; nf < 3; nf++)
        acc[mf][nf] = __builtin_amdgcn_mfma_f32_16x16x32_bf16(a[mf], b[nf],
                                                              acc[mf][nf], 0, 0, 0);
    __builtin_amdgcn_s_setprio(0);
    __builtin_amdgcn_s_barrier();

    // ---- phase 4: read A.k1 m4-7 ; no stage ; vmcnt(2)
#pragma unroll
    for (int mf = 0; mf < 4; mf++)
      a2[mf] = *(const bf16x8*)&sA[db][1][(wr * 128 + (mf + 4) * 16 + lr) * 32 + gsw];
    __builtin_amdgcn_s_barrier();
    asm volatile("s_waitcnt lgkmcnt(0)" ::: "memory");
    __builtin_amdgcn_sched_barrier(0);
    __builtin_amdgcn_s_setprio(1);
#pragma unroll
    for (int mf = 0; mf < 4; mf++)
#pragma unroll
      for (int nf = 0; nf < 3; nf++)
        acc[mf + 4][nf] = __builtin_amdgcn_mfma_f32_16x16x32_bf16(
            a2[mf], b[nf], acc[mf + 4][nf], 0, 0, 0);
    __builtin_amdgcn_s_setprio(0);
    asm volatile("s_waitcnt vmcnt(2)" ::: "memory");
    __builtin_amdgcn_s_barrier();
  }

  // epilogue
#pragma unroll
  for (int mf = 0; mf < 8; mf++) {
#pragma unroll
    for (int nf = 0; nf < 3; nf++) {
      int gm0 = bm + wr * 128 + mf * 16 + lg * 4;
      int gn = bn + wc * 48 + nf * 16 + lr;
#pragma unroll
      for (int j = 0; j < 4; j++) {
        float v = acc[mf][nf][j];
        int gm = gm0 + j;
        if (EPI == 0) {
          Cf[(size_t)gm * N + gn] = v;
        } else {
          int which = gn >> 11, rem = gn & 2047;
          int h = rem >> 7, d = rem & 127;
          int b = gm >> 11, s = gm & 2047;
          unsigned short* dst = which == 0 ? q_out : (which == 1 ? k_out : v_out);
          dst[(((size_t)(b * 16 + h)) * 2048 + s) * 128 + d] = f2bf(v);
        }
      }
    }
  }
}

// ---------------------------------------------------------------- flash attention (32x32 MFMA)
__global__ __launch_bounds__(256, 2) void attn_k(
    const unsigned short* __restrict__ Q, const unsigned short* __restrict__ K,
    const unsigned short* __restrict__ Vt, unsigned short* __restrict__ ctx) {
  __shared__ unsigned short sK[2][64 * 128];  // 2 x 16KB
  __shared__ unsigned short sV[2][128 * 64];  // 2 x 16KB

  const int qt = blockIdx.x, bh = blockIdx.y;
  const int t = threadIdx.x;
  const int w = t >> 6, l = t & 63;
  const int lq = l & 31;   // q-row (QK) / d-col (PV)
  const int h5 = l >> 5;   // half-wave select
  const int b = bh >> 4, hh = bh & 15;
  const int q0 = qt * 128 + w * 32;
  const unsigned short* Qp = Q + ((size_t)bh * 2048 + q0) * 128;
  const unsigned short* Kbh = K + (size_t)bh * 2048 * 128;
  const unsigned short* Vbh = Vt + (size_t)bh * 128 * 2048;

  int gko[4], gvo[4];
#pragma unroll
  for (int i = 0; i < 4; i++) {
    int p = i * 256 + t;
    int rK = p >> 4, cK = p & 15;
    gko[i] = rK * 128 + ((cK ^ (rK & 7)) * 8);
    int rV = p >> 3, cV = p & 7;
    gvo[i] = rV * 2048 + ((cV ^ (rV & 7)) * 8);
  }

  bf16x8 qf[8];
#pragma unroll
  for (int st = 0; st < 8; st++)
    qf[st] = *(const bf16x8*)(Qp + lq * 128 + st * 16 + h5 * 8);

  f32x16 o[4];
#pragma unroll
  for (int db = 0; db < 4; db++) o[db] = (f32x16)0.0f;
  float m_r = -1e30f, l_r = 0.0f;

#define STAGE_KV(buf, kv)                                                      \
  do {                                                                         \
    _Pragma("unroll") for (int i = 0; i < 4; i++)                              \
        GLOAD16(Kbh + (size_t)(kv)*128 + gko[i],                               \
                sK[buf] + (i * 256 + t) * 8);                                  \
    _Pragma("unroll") for (int i = 0; i < 4; i++)                              \
        GLOAD16(Vbh + (size_t)(kv) + gvo[i], sV[buf] + (i * 256 + t) * 8);     \
  } while (0)

  STAGE_KV(0, 0);
  __syncthreads();

  for (int it = 0; it < 32; ++it) {
    const int cur = it & 1;
    if (it < 31) STAGE_KV(cur ^ 1, (it + 1) * 64);

    const char* kbuf = (const char*)sK[cur];
    const char* vbuf = (const char*)sV[cur];

    f32x16 s2[2];
#pragma unroll
    for (int kb2 = 0; kb2 < 2; kb2++) {
      s2[kb2] = (f32x16)0.0f;
      const int rr = kb2 * 32 + lq;
      const int swzz = (rr & 7) << 4;
#pragma unroll
      for (int st = 0; st < 8; st++) {
        bf16x8 kf = *(const bf16x8*)(kbuf + rr * 256 + ((st * 32 + h5 * 16) ^ swzz));
        s2[kb2] = __builtin_amdgcn_mfma_f32_32x32x16_bf16(kf, qf[st], s2[kb2], 0, 0, 0);
      }
    }

    float sm[32];
#pragma unroll
    for (int kb2 = 0; kb2 < 2; kb2++)
#pragma unroll
      for (int r = 0; r < 16; r++) sm[kb2 * 16 + r] = s2[kb2][r];

    float tmax = sm[0];
#pragma unroll
    for (int i = 1; i < 32; i++) tmax = fmaxf(tmax, sm[i]);
    tmax = fmaxf(tmax, __shfl_xor(tmax, 32));

    if (!__all(tmax <= m_r + 8.0f)) {
      float m_new = fmaxf(m_r, tmax);
      float fac = exp2f(m_r - m_new);
      l_r *= fac;
      float fo[16];
#pragma unroll
      for (int r = 0; r < 16; r++)
        fo[r] = __shfl(fac, (r & 3) + 8 * (r >> 2) + 4 * h5);
#pragma unroll
      for (int db = 0; db < 4; db++)
#pragma unroll
        for (int r = 0; r < 16; r++) o[db][r] *= fo[r];
      m_r = m_new;
    }

    float psum = 0.0f;
#pragma unroll
    for (int i = 0; i < 32; i++) {
      sm[i] = exp2f(sm[i] - m_r);
      psum += sm[i];
    }
    psum += __shfl_xor(psum, 32);
    l_r += psum;

    uint32_t wAp[2][4], wBp[2][4];
#pragma unroll
    for (int kb2 = 0; kb2 < 2; kb2++)
#pragma unroll
      for (int rq = 0; rq < 4; rq++) {
        wAp[kb2][rq] = cvt_pk_bf16(sm[kb2 * 16 + rq * 4 + 0], sm[kb2 * 16 + rq * 4 + 1]);
        wBp[kb2][rq] = cvt_pk_bf16(sm[kb2 * 16 + rq * 4 + 2], sm[kb2 * 16 + rq * 4 + 3]);
      }

#pragma unroll
    for (int st = 0; st < 4; st++) {
      const int kb2 = st >> 1, p2 = (st & 1) * 2;
      uint32_t keepA = h5 ? wAp[kb2][p2 + 1] : wAp[kb2][p2];
      uint32_t keepB = h5 ? wBp[kb2][p2 + 1] : wBp[kb2][p2];
      uint32_t sendA = h5 ? wAp[kb2][p2] : wAp[kb2][p2 + 1];
      uint32_t sendB = h5 ? wBp[kb2][p2] : wBp[kb2][p2 + 1];
      uint32_t partA = __shfl_xor(sendA, 32);
      uint32_t partB = __shfl_xor(sendB, 32);
      union {
        uint32_t u[4];
        bf16x8 v;
      } pu;
      pu.u[0] = h5 ? partA : keepA;
      pu.u[1] = h5 ? partB : keepB;
      pu.u[2] = h5 ? keepA : partA;
      pu.u[3] = h5 ? keepB : partB;
#pragma unroll
      for (int db = 0; db < 4; db++) {
        const int rv = db * 32 + lq;
        const int swzz = (rv & 7) << 4;
        bf16x8 vb = *(const bf16x8*)(vbuf + rv * 128 + ((st * 32 + h5 * 16) ^ swzz));
        o[db] = __builtin_amdgcn_mfma_f32_32x32x16_bf16(pu.v, vb, o[db], 0, 0, 0);
      }
    }
    __syncthreads();
  }

  float inv = 1.0f / l_r;
  float io[16];
#pragma unroll
  for (int r = 0; r < 16; r++)
    io[r] = __shfl(inv, (r & 3) + 8 * (r >> 2) + 4 * h5);
#pragma unroll
  for (int db = 0; db < 4; db++) {
#pragma unroll
    for (int r = 0; r < 16; r++) {
      int s = q0 + (r & 3) + 8 * (r >> 2) + 4 * h5;
      ctx[((size_t)(b * 2048 + s)) * 2048 + hh * 128 + db * 32 + lq] =
          f2bf(o[db][r] * io[r]);
    }
  }
}

// ---------------------------------------------------------------- launch
extern "C" void kernel_launch(void* const* d_in, const int* in_sizes, int n_in,
                              void* d_out, int out_size, void* d_ws,
                              size_t ws_size, hipStream_t stream) {
  const float* x = (const float*)d_in[0];
  const float* Wq = (const float*)d_in[1];
  const float* Wk = (const float*)d_in[2];
  const float* Wv = (const float*)d_in[3];
  const float* Wo = (const float*)d_in[4];
  float* out = (float*)d_out;

  const size_t BS = 4096;  // B*S
  const size_t D = 2048;

  char* p = (char*)d_ws;
  unsigned short* xb = (unsigned short*)p;   p += BS * D * 2;
  unsigned short* wqkv = (unsigned short*)p; p += 3 * D * D * 2;
  unsigned short* wo = (unsigned short*)p;   p += D * D * 2;
  unsigned short* qb = (unsigned short*)p;   p += BS * D * 2;
  unsigned short* kb = (unsigned short*)p;   p += BS * D * 2;
  unsigned short* vb = (unsigned short*)p;   p += BS * D * 2;
  float* ctab = (float*)p;                   p += 2048 * 64 * 4;
  float* stab = (float*)p;                   p += 2048 * 64 * 4;
  unsigned short* vt = wqkv;  // reuse (dead after gemm256)
  unsigned short* ctx = xb;   // reuse (dead after gemm256)

  // fused convert: 25,165,824 elems / 4 per thread / 256 per block
  cvt_all<<<24576, 256, 0, stream>>>(x, Wq, Wk, Wv, Wo, xb, wqkv, wo);
  rope_table_k<<<512, 256, 0, stream>>>(ctab, stab);

  // QKV projection: M=4096 (16 tiles of 256), N=6144 (32 tiles of 192) -> 512 blocks
  gemm256<1><<<512, 512, 0, stream>>>(xb, wqkv, nullptr, qb, kb, vb, 4096, 6144,
                                      2048, 16);
  rope_apply_k<<<8192, 256, 0, stream>>>(qb, kb, ctab, stab);
  transpose_v_k<<<dim3(32, 32, 2), 256, 0, stream>>>(vb, vt);
  attn_k<<<dim3(16, 32), 256, 0, stream>>>(qb, kb, vt, ctx);
  gemm_bt<0><<<dim3(32, 16), 256, 0, stream>>>(ctx, wo, out, 4096, 2048, 2048);
}